// Round 5
// baseline (408.134 us; speedup 1.0000x reference)
//
#include <hip/hip_runtime.h>
#include <math.h>

constexpr int Cc = 3, Hh = 256;
constexpr int NX = 393216;   // 2*3*256*256
constexpr int R = 4;         // rows per tile
constexpr int NBLK = 384;    // 6 images * 64 tiles
constexpr int KSTEPS = 50;

using u64 = unsigned long long;

__device__ __forceinline__ float4 ld4(const float* p, int i) { return ((const float4*)p)[i]; }
__device__ __forceinline__ void st4(float* p, int i, float4 v) { ((float4*)p)[i] = v; }
__device__ __forceinline__ float4 mk4(float a, float b, float c, float d) { return make_float4(a, b, c, d); }

// Coherent (cross-XCD) 16B access: relaxed agent-scope atomics lower to sc1
// loads/stores that bypass the non-coherent per-XCD L2 — no cache flushes.
__device__ __forceinline__ float4 ld4_coh(const float* p) {
    union { float4 f; u64 q[2]; } r;
    const u64* q = (const u64*)p;
    r.q[0] = __hip_atomic_load(q + 0, __ATOMIC_RELAXED, __HIP_MEMORY_SCOPE_AGENT);
    r.q[1] = __hip_atomic_load(q + 1, __ATOMIC_RELAXED, __HIP_MEMORY_SCOPE_AGENT);
    return r.f;
}
__device__ __forceinline__ void st4_coh(float* p, float4 v) {
    union { float4 f; u64 q[2]; } r; r.f = v;
    u64* q = (u64*)p;
    __hip_atomic_store(q + 0, r.q[0], __ATOMIC_RELAXED, __HIP_MEMORY_SCOPE_AGENT);
    __hip_atomic_store(q + 1, r.q[1], __ATOMIC_RELAXED, __HIP_MEMORY_SCOPE_AGENT);
}

__global__ void zero_flags(unsigned* flags) { flags[threadIdx.x] = 0u; }

__global__ void __launch_bounds__(256) cp_persist(
    const float* __restrict__ y, const float* __restrict__ lambd,
    float* __restrict__ xout, float* __restrict__ xtout, float* __restrict__ uout,
    float* __restrict__ v0f, float* __restrict__ v1f, float* __restrict__ v0l,
    float* __restrict__ xf, float* __restrict__ parts, unsigned* __restrict__ flags)
{
    __shared__ float sxt[5 * 256];
    __shared__ float sv0[4 * 256];
    __shared__ float2 pw[4];
    const int tid = threadIdx.x;
    const int blk = blockIdx.x;
    const int bc = blk >> 6;
    const int tile = blk & 63;
    const int r0 = tile * R;
    const int c4 = tid & 63;
    const int trow = tid >> 6;
    const int b = (bc >= Cc) ? 1 : 0;
    const int gh = r0 + trow;
    const int j4 = bc * 16384 + gh * 64 + c4;
    const int iv4 = bc * 32768 + gh * 64 + c4;

    const float lamb = expf(lambd[0]);

    // ---------------- init: x=y, v = nabla(y) (= u_0, since xt_0=0) ----------------
    float4 yv = ld4(y, j4);
    float4 xreg = yv;
    float4 yhalo = mk4(0.f, 0.f, 0.f, 0.f);
    if (trow == 0 && tile < 63) yhalo = ld4(y, bc * 16384 + (r0 + 4) * 64 + c4);
    float4 v0, v1;
    {
        float4 dh = mk4(0.f, 0.f, 0.f, 0.f);
        if (gh < Hh - 1) {
            float4 yn = ld4(y, j4 + 64);
            dh.x = yn.x - yv.x; dh.y = yn.y - yv.y; dh.z = yn.z - yv.z; dh.w = yn.w - yv.w;
        }
        float4 dw;
        dw.x = yv.y - yv.x; dw.y = yv.z - yv.y; dw.z = yv.w - yv.z;
        float ynx = __shfl_down(yv.x, 1, 64);
        dw.w = (c4 < 63) ? (ynx - yv.w) : 0.f;
        v0 = dh; v1 = dw;
    }
    ((float4*)(sv0 + trow * 256))[c4] = v0;
    if (trow == 0) {
        st4_coh(v0f + (0 * NBLK + blk) * 256 + c4 * 4, v0);
        st4_coh(v1f + (0 * NBLK + blk) * 256 + c4 * 4, v1);
        st4_coh(xf  + (0 * NBLK + blk) * 256 + c4 * 4, xreg);
    }
    if (trow == 3) st4_coh(v0l + (0 * NBLK + blk) * 256 + c4 * 4, v0);
    {
        float pa0 = v0.x*v0.x + v0.y*v0.y + v0.z*v0.z + v0.w*v0.w;
        float pa1 = v1.x*v1.x + v1.y*v1.y + v1.z*v1.z + v1.w*v1.w;
        #pragma unroll
        for (int m = 1; m < 64; m <<= 1) {
            pa0 += __shfl_xor(pa0, m, 64);
            pa1 += __shfl_xor(pa1, m, 64);
        }
        if (c4 == 0) pw[trow] = make_float2(pa0, pa1);
        __syncthreads();
        if (tid == 0) {
            float q0 = pw[0].x + pw[1].x + pw[2].x + pw[3].x;
            float q1 = pw[0].y + pw[1].y + pw[2].y + pw[3].y;
            st4_coh(parts + (0 * NBLK + blk) * 4, b ? mk4(0.f, 0.f, q0, q1) : mk4(q0, q1, 0.f, 0.f));
        }
    }
    asm volatile("s_waitcnt vmcnt(0)" ::: "memory");
    __syncthreads();
    if (tid == 0) __hip_atomic_store(flags + blk, 1u, __ATOMIC_RELAXED, __HIP_MEMORY_SCOPE_AGENT);

    float sigma = 0.20412414523193150818f;   // 0.5/sqrt(6)
    float tau   = sigma;
    float4 u0, u1;

    for (int s = 1; s <= KSTEPS; ++s) {
        // ---------------- global barrier: all flags >= s ----------------
        if (tid < 64) {
            for (;;) {
                unsigned f0 = __hip_atomic_load(flags + c4,       __ATOMIC_RELAXED, __HIP_MEMORY_SCOPE_AGENT);
                unsigned f1 = __hip_atomic_load(flags + c4 + 64,  __ATOMIC_RELAXED, __HIP_MEMORY_SCOPE_AGENT);
                unsigned f2 = __hip_atomic_load(flags + c4 + 128, __ATOMIC_RELAXED, __HIP_MEMORY_SCOPE_AGENT);
                unsigned f3 = __hip_atomic_load(flags + c4 + 192, __ATOMIC_RELAXED, __HIP_MEMORY_SCOPE_AGENT);
                unsigned f4 = __hip_atomic_load(flags + c4 + 256, __ATOMIC_RELAXED, __HIP_MEMORY_SCOPE_AGENT);
                unsigned f5 = __hip_atomic_load(flags + c4 + 320, __ATOMIC_RELAXED, __HIP_MEMORY_SCOPE_AGENT);
                unsigned m01 = f0 < f1 ? f0 : f1;
                unsigned m23 = f2 < f3 ? f2 : f3;
                unsigned m45 = f4 < f5 ? f4 : f5;
                unsigned m = m01 < m23 ? m01 : m23; m = m < m45 ? m : m45;
                if (__all(m >= (unsigned)s)) break;
                __builtin_amdgcn_s_sleep(1);
            }
        }
        __syncthreads();
        const int P = (s - 1) & 1;

        // early coherent neighbor loads (overlap with scales below)
        float4 vmtop = mk4(0.f, 0.f, 0.f, 0.f);
        float4 v0h = vmtop, v1h = vmtop, xoh = vmtop;
        if (trow == 0) {
            if (tile > 0) vmtop = ld4_coh(v0l + (P * NBLK + blk - 1) * 256 + c4 * 4);
            if (tile < 63) {
                v0h = ld4_coh(v0f + (P * NBLK + blk + 1) * 256 + c4 * 4);
                v1h = ld4_coh(v1f + (P * NBLK + blk + 1) * 256 + c4 * 4);
                xoh = ld4_coh(xf  + (P * NBLK + blk + 1) * 256 + c4 * 4);
            }
        }

        // scales: redundant all-partials reduce (fixed-order + butterfly, deterministic)
        float4 S = mk4(0.f, 0.f, 0.f, 0.f);
        #pragma unroll
        for (int k = 0; k < 6; ++k) {
            float4 p = ld4_coh(parts + (P * NBLK + (c4 + 64 * k)) * 4);
            S.x += p.x; S.y += p.y; S.z += p.z; S.w += p.w;
        }
        #pragma unroll
        for (int m = 1; m < 64; m <<= 1) {
            S.x += __shfl_xor(S.x, m, 64);
            S.y += __shfl_xor(S.y, m, 64);
            S.z += __shfl_xor(S.z, m, 64);
            S.w += __shfl_xor(S.w, m, 64);
        }
        const float s0 = lamb / fmaxf(sqrtf(b ? S.z : S.x), lamb);
        const float s1 = lamb / fmaxf(sqrtf(b ? S.w : S.y), lamb);
        const float chi = 1.0f / sqrtf(1.0f + tau);
        const float inv = 1.0f / (1.0f + tau);
        const float opc = 1.0f + chi;

        // ---------------- phase B (step s-1), own row ----------------
        u0.x = v0.x*s0; u0.y = v0.y*s0; u0.z = v0.z*s0; u0.w = v0.w*s0;
        u1.x = v1.x*s1; u1.y = v1.y*s1; u1.z = v1.z*s1; u1.w = v1.w*s1;
        float4 vm = (trow > 0) ? ((float4*)(sv0 + (trow - 1) * 256))[c4] : vmtop;
        float nt0 = 0.f, nt1 = 0.f, nt2 = 0.f, nt3 = 0.f;
        if (gh > 0) { nt0 += vm.x*s0; nt1 += vm.y*s0; nt2 += vm.z*s0; nt3 += vm.w*s0; }
        if (gh < Hh - 1) { nt0 -= u0.x; nt1 -= u0.y; nt2 -= u0.z; nt3 -= u0.w; }
        float ul = __shfl_up(u1.w, 1, 64);
        if (c4 > 0) nt0 += ul;
        nt1 += u1.x; nt2 += u1.y; nt3 += u1.z;
        nt0 -= u1.x; nt1 -= u1.y; nt2 -= u1.z;
        if (c4 < 63) nt3 -= u1.w;
        float4 xp, xtp;
        xp.x = (xreg.x + tau * (yv.x - nt0)) * inv;
        xp.y = (xreg.y + tau * (yv.y - nt1)) * inv;
        xp.z = (xreg.z + tau * (yv.z - nt2)) * inv;
        xp.w = (xreg.w + tau * (yv.w - nt3)) * inv;
        xtp.x = opc * xp.x - chi * xreg.x;
        xtp.y = opc * xp.y - chi * xreg.y;
        xtp.z = opc * xp.z - chi * xreg.z;
        xtp.w = opc * xp.w - chi * xreg.w;

        if (s == KSTEPS) {
            st4(xout, j4, xp);
            st4(xtout, j4, xtp);
            st4(uout, iv4, u0);
            st4(uout, iv4 + 16384, u1);
            break;
        }
        xreg = xp;
        if (trow > 0) ((float4*)(sxt + trow * 256))[c4] = xtp;
        if (trow == 0) st4_coh(xf + ((s & 1) * NBLK + blk) * 256 + c4 * 4, xp);

        // ---- phase B, redundant halo row r0+4 (wave 0, interior rows only) ----
        if (trow == 0 && tile < 63) {
            float4 h0, h1;
            h0.x = v0h.x*s0; h0.y = v0h.y*s0; h0.z = v0h.z*s0; h0.w = v0h.w*s0;
            h1.x = v1h.x*s1; h1.y = v1h.y*s1; h1.z = v1h.z*s1; h1.w = v1h.w*s1;
            float4 vmh = ((float4*)(sv0 + 3 * 256))[c4];
            float h_nt0 = vmh.x*s0 - h0.x, h_nt1 = vmh.y*s0 - h0.y,
                  h_nt2 = vmh.z*s0 - h0.z, h_nt3 = vmh.w*s0 - h0.w;
            float hul = __shfl_up(h1.w, 1, 64);
            if (c4 > 0) h_nt0 += hul;
            h_nt1 += h1.x; h_nt2 += h1.y; h_nt3 += h1.z;
            h_nt0 -= h1.x; h_nt1 -= h1.y; h_nt2 -= h1.z;
            if (c4 < 63) h_nt3 -= h1.w;
            float4 xph, xth;
            xph.x = (xoh.x + tau * (yhalo.x - h_nt0)) * inv;
            xph.y = (xoh.y + tau * (yhalo.y - h_nt1)) * inv;
            xph.z = (xoh.z + tau * (yhalo.z - h_nt2)) * inv;
            xph.w = (xoh.w + tau * (yhalo.w - h_nt3)) * inv;
            xth.x = opc * xph.x - chi * xoh.x;
            xth.y = opc * xph.y - chi * xoh.y;
            xth.z = opc * xph.z - chi * xoh.z;
            xth.w = opc * xph.w - chi * xoh.w;
            ((float4*)(sxt + 4 * 256))[c4] = xth;
        }
        __syncthreads();

        // ---------------- phase A (step s) ----------------
        const float sigs = sigma / chi;
        float4 dh = mk4(0.f, 0.f, 0.f, 0.f);
        if (gh < Hh - 1) {
            float4 xn = ((const float4*)(sxt + (trow + 1) * 256))[c4];
            dh.x = xn.x - xtp.x; dh.y = xn.y - xtp.y; dh.z = xn.z - xtp.z; dh.w = xn.w - xtp.w;
        }
        float4 dw;
        dw.x = xtp.y - xtp.x; dw.y = xtp.z - xtp.y; dw.z = xtp.w - xtp.z;
        float xnx = __shfl_down(xtp.x, 1, 64);
        dw.w = (c4 < 63) ? (xnx - xtp.w) : 0.f;
        v0.x = fmaf(sigs, dh.x, u0.x); v0.y = fmaf(sigs, dh.y, u0.y);
        v0.z = fmaf(sigs, dh.z, u0.z); v0.w = fmaf(sigs, dh.w, u0.w);
        v1.x = fmaf(sigs, dw.x, u1.x); v1.y = fmaf(sigs, dw.y, u1.y);
        v1.z = fmaf(sigs, dw.z, u1.z); v1.w = fmaf(sigs, dw.w, u1.w);
        ((float4*)(sv0 + trow * 256))[c4] = v0;
        if (trow == 0) {
            st4_coh(v0f + ((s & 1) * NBLK + blk) * 256 + c4 * 4, v0);
            st4_coh(v1f + ((s & 1) * NBLK + blk) * 256 + c4 * 4, v1);
        }
        if (trow == 3) st4_coh(v0l + ((s & 1) * NBLK + blk) * 256 + c4 * 4, v0);
        float pa0 = v0.x*v0.x + v0.y*v0.y + v0.z*v0.z + v0.w*v0.w;
        float pa1 = v1.x*v1.x + v1.y*v1.y + v1.z*v1.z + v1.w*v1.w;
        #pragma unroll
        for (int m = 1; m < 64; m <<= 1) {
            pa0 += __shfl_xor(pa0, m, 64);
            pa1 += __shfl_xor(pa1, m, 64);
        }
        if (c4 == 0) pw[trow] = make_float2(pa0, pa1);
        __syncthreads();
        if (tid == 0) {
            float q0 = pw[0].x + pw[1].x + pw[2].x + pw[3].x;
            float q1 = pw[0].y + pw[1].y + pw[2].y + pw[3].y;
            st4_coh(parts + ((s & 1) * NBLK + blk) * 4, b ? mk4(0.f, 0.f, q0, q1) : mk4(q0, q1, 0.f, 0.f));
        }
        asm volatile("s_waitcnt vmcnt(0)" ::: "memory");
        __syncthreads();
        if (tid == 0) __hip_atomic_store(flags + blk, (unsigned)(s + 1), __ATOMIC_RELAXED, __HIP_MEMORY_SCOPE_AGENT);

        tau *= chi;
        sigma = sigs;
    }
}

extern "C" void kernel_launch(void* const* d_in, const int* in_sizes, int n_in,
                              void* d_out, int out_size, void* d_ws, size_t ws_size,
                              hipStream_t stream) {
    (void)in_sizes; (void)n_in; (void)out_size; (void)ws_size;
    const float* y     = (const float*)d_in[0];
    const float* lambd = (const float*)d_in[1];
    float* xout  = (float*)d_out;       // [0, NX)
    float* xtout = xout + NX;           // [NX, 2NX)
    float* uout  = xout + 2 * NX;       // [2NX, 2NX+NU)

    float* v0f   = (float*)d_ws;                 // [2][NBLK][256]
    float* v1f   = v0f + 2 * NBLK * 256;
    float* v0l   = v1f + 2 * NBLK * 256;
    float* xf    = v0l + 2 * NBLK * 256;
    float* parts = xf  + 2 * NBLK * 256;         // [2][NBLK][4]
    unsigned* flags = (unsigned*)(parts + 2 * NBLK * 4);  // [NBLK]

    zero_flags<<<1, NBLK, 0, stream>>>(flags);
    cp_persist<<<NBLK, 256, 0, stream>>>(y, lambd, xout, xtout, uout,
                                         v0f, v1f, v0l, xf, parts, flags);
}

// Round 6
// 345.590 us; speedup vs baseline: 1.1810x; 1.1810x over previous
//
#include <hip/hip_runtime.h>
#include <math.h>

constexpr int Cc = 3, Hh = 256;
constexpr int NX = 393216;   // 2*3*256*256
constexpr int R = 8;         // rows per block
constexpr int NBLK = 192;    // 6 images * 32 tiles  (<= 256 CUs: 1 block/CU)
constexpr int KSTEPS = 50;

using u64 = unsigned long long;

__device__ __forceinline__ float4 ld4(const float* p, int i) { return ((const float4*)p)[i]; }
__device__ __forceinline__ void st4(float* p, int i, float4 v) { ((float4*)p)[i] = v; }
__device__ __forceinline__ float4 mk4(float a, float b, float c, float d) { return make_float4(a, b, c, d); }

// Coherent (cross-XCD) access via relaxed agent-scope atomics (sc1, bypass L2).
__device__ __forceinline__ float4 ld4_coh(const float* p) {
    union { float4 f; u64 q[2]; } r;
    const u64* q = (const u64*)p;
    r.q[0] = __hip_atomic_load(q + 0, __ATOMIC_RELAXED, __HIP_MEMORY_SCOPE_AGENT);
    r.q[1] = __hip_atomic_load(q + 1, __ATOMIC_RELAXED, __HIP_MEMORY_SCOPE_AGENT);
    return r.f;
}
__device__ __forceinline__ void st4_coh(float* p, float4 v) {
    union { float4 f; u64 q[2]; } r; r.f = v;
    u64* q = (u64*)p;
    __hip_atomic_store(q + 0, r.q[0], __ATOMIC_RELAXED, __HIP_MEMORY_SCOPE_AGENT);
    __hip_atomic_store(q + 1, r.q[1], __ATOMIC_RELAXED, __HIP_MEMORY_SCOPE_AGENT);
}

__global__ void zero_cnt(unsigned* cnt) { *cnt = 0u; }

__global__ void __launch_bounds__(256) cp_persist(
    const float* __restrict__ y, const float* __restrict__ lambd,
    float* __restrict__ xout, float* __restrict__ xtout, float* __restrict__ uout,
    float* __restrict__ v0f, float* __restrict__ v1f, float* __restrict__ v0l,
    float* __restrict__ xf, float* __restrict__ parts, unsigned* __restrict__ cnt)
{
    __shared__ float sxt[9 * 256];
    __shared__ float sv0[8 * 256];
    __shared__ float2 pw[4];
    const int tid = threadIdx.x;
    const int blk = blockIdx.x;
    const int bc = blk >> 5;           // image index [0,6)
    const int tile = blk & 31;         // [0,32)
    const int r0 = tile * R;
    const int c4 = tid & 63;
    const int trow = tid >> 6;         // [0,4)
    const int b = (bc >= Cc) ? 1 : 0;

    const float lamb = expf(lambd[0]);

    float4 yv[2], xreg[2], v0[2], v1[2], u0[2], u1[2], xtp[2];
    float4 yhalo = mk4(0.f, 0.f, 0.f, 0.f);
    if (trow == 0 && tile < 31) yhalo = ld4(y, bc * 16384 + (r0 + 8) * 64 + c4);

    // ---------------- init: x=y, v = nabla(y) (xt_0 = 0 so v_0 = u_0) ----------------
    {
        float pa0 = 0.f, pa1 = 0.f;
        #pragma unroll
        for (int k = 0; k < 2; ++k) {
            const int rr = trow + 4 * k;
            const int gh = r0 + rr;
            const int j4 = bc * 16384 + gh * 64 + c4;
            yv[k] = ld4(y, j4);
            xreg[k] = yv[k];
            float4 dh = mk4(0.f, 0.f, 0.f, 0.f);
            if (gh < Hh - 1) {
                float4 yn = ld4(y, j4 + 64);
                dh.x = yn.x - yv[k].x; dh.y = yn.y - yv[k].y;
                dh.z = yn.z - yv[k].z; dh.w = yn.w - yv[k].w;
            }
            float4 dw;
            dw.x = yv[k].y - yv[k].x; dw.y = yv[k].z - yv[k].y; dw.z = yv[k].w - yv[k].z;
            float ynx = __shfl_down(yv[k].x, 1, 64);
            dw.w = (c4 < 63) ? (ynx - yv[k].w) : 0.f;
            v0[k] = dh; v1[k] = dw;
            ((float4*)(sv0 + rr * 256))[c4] = dh;
            pa0 += dh.x*dh.x + dh.y*dh.y + dh.z*dh.z + dh.w*dh.w;
            pa1 += dw.x*dw.x + dw.y*dw.y + dw.z*dw.z + dw.w*dw.w;
        }
        if (trow == 0) {
            st4_coh(v0f + blk * 256 + c4 * 4, v0[0]);
            st4_coh(v1f + blk * 256 + c4 * 4, v1[0]);
            st4_coh(xf  + blk * 256 + c4 * 4, xreg[0]);
        }
        if (trow == 3) st4_coh(v0l + blk * 256 + c4 * 4, v0[1]);   // row 7
        #pragma unroll
        for (int m = 1; m < 64; m <<= 1) {
            pa0 += __shfl_xor(pa0, m, 64);
            pa1 += __shfl_xor(pa1, m, 64);
        }
        if (c4 == 0) pw[trow] = make_float2(pa0, pa1);
        __syncthreads();
        if (tid == 0) {
            float q0 = pw[0].x + pw[1].x + pw[2].x + pw[3].x;
            float q1 = pw[0].y + pw[1].y + pw[2].y + pw[3].y;
            st4_coh(parts + blk * 4, b ? mk4(0.f, 0.f, q0, q1) : mk4(q0, q1, 0.f, 0.f));
        }
        asm volatile("s_waitcnt vmcnt(0)" ::: "memory");
        __syncthreads();
        if (tid == 0) __hip_atomic_fetch_add(cnt, 1u, __ATOMIC_RELAXED, __HIP_MEMORY_SCOPE_AGENT);
    }

    float sigma = 0.20412414523193150818f;   // 0.5/sqrt(6)
    float tau   = sigma;

    for (int s = 1; s <= KSTEPS; ++s) {
        // ---------------- barrier: cnt >= 192*s (1 coalesced load/poll) ----------------
        if (tid < 64) {
            const unsigned tgt = (unsigned)(NBLK * s);
            while (__hip_atomic_load(cnt, __ATOMIC_RELAXED, __HIP_MEMORY_SCOPE_AGENT) < tgt)
                __builtin_amdgcn_s_sleep(1);
        }
        __syncthreads();
        asm volatile("" ::: "memory");

        const int P = (s - 1) & 1, Q = s & 1;

        // early coherent neighbor loads (overlap with scales)
        float4 vmtop = mk4(0.f, 0.f, 0.f, 0.f);
        float4 v0h = vmtop, v1h = vmtop, xoh = vmtop;
        if (trow == 0) {
            if (tile > 0) vmtop = ld4_coh(v0l + (P * NBLK + blk - 1) * 256 + c4 * 4);
            if (tile < 31) {
                v0h = ld4_coh(v0f + (P * NBLK + blk + 1) * 256 + c4 * 4);
                v1h = ld4_coh(v1f + (P * NBLK + blk + 1) * 256 + c4 * 4);
                xoh = ld4_coh(xf  + (P * NBLK + blk + 1) * 256 + c4 * 4);
            }
        }

        // scales: redundant fixed-order reduce of all 192 partials + butterfly
        float4 S = mk4(0.f, 0.f, 0.f, 0.f);
        #pragma unroll
        for (int kk = 0; kk < 3; ++kk) {
            float4 p = ld4_coh(parts + (P * NBLK + c4 + 64 * kk) * 4);
            S.x += p.x; S.y += p.y; S.z += p.z; S.w += p.w;
        }
        #pragma unroll
        for (int m = 1; m < 64; m <<= 1) {
            S.x += __shfl_xor(S.x, m, 64);
            S.y += __shfl_xor(S.y, m, 64);
            S.z += __shfl_xor(S.z, m, 64);
            S.w += __shfl_xor(S.w, m, 64);
        }
        const float s0 = lamb / fmaxf(sqrtf(b ? S.z : S.x), lamb);
        const float s1 = lamb / fmaxf(sqrtf(b ? S.w : S.y), lamb);
        const float chi = 1.0f / sqrtf(1.0f + tau);
        const float inv = 1.0f / (1.0f + tau);
        const float opc = 1.0f + chi;

        // ---------------- phase B (step s-1) ----------------
        #pragma unroll
        for (int k = 0; k < 2; ++k) {
            const int rr = trow + 4 * k;
            const int gh = r0 + rr;
            float4 uu0, uu1;
            uu0.x = v0[k].x*s0; uu0.y = v0[k].y*s0; uu0.z = v0[k].z*s0; uu0.w = v0[k].w*s0;
            uu1.x = v1[k].x*s1; uu1.y = v1[k].y*s1; uu1.z = v1[k].z*s1; uu1.w = v1[k].w*s1;
            float4 vm = (k == 0) ? ((trow > 0) ? ((float4*)(sv0 + (trow - 1) * 256))[c4] : vmtop)
                                 : ((float4*)(sv0 + (trow + 3) * 256))[c4];
            float nt0 = 0.f, nt1 = 0.f, nt2 = 0.f, nt3 = 0.f;
            if (gh > 0) { nt0 += vm.x*s0; nt1 += vm.y*s0; nt2 += vm.z*s0; nt3 += vm.w*s0; }
            if (gh < Hh - 1) { nt0 -= uu0.x; nt1 -= uu0.y; nt2 -= uu0.z; nt3 -= uu0.w; }
            float ul = __shfl_up(uu1.w, 1, 64);
            if (c4 > 0) nt0 += ul;
            nt1 += uu1.x; nt2 += uu1.y; nt3 += uu1.z;
            nt0 -= uu1.x; nt1 -= uu1.y; nt2 -= uu1.z;
            if (c4 < 63) nt3 -= uu1.w;
            float4 xp;
            xp.x = (xreg[k].x + tau * (yv[k].x - nt0)) * inv;
            xp.y = (xreg[k].y + tau * (yv[k].y - nt1)) * inv;
            xp.z = (xreg[k].z + tau * (yv[k].z - nt2)) * inv;
            xp.w = (xreg[k].w + tau * (yv[k].w - nt3)) * inv;
            xtp[k].x = opc * xp.x - chi * xreg[k].x;
            xtp[k].y = opc * xp.y - chi * xreg[k].y;
            xtp[k].z = opc * xp.z - chi * xreg[k].z;
            xtp[k].w = opc * xp.w - chi * xreg[k].w;
            u0[k] = uu0; u1[k] = uu1;
            if (s == KSTEPS) {
                const int j4 = bc * 16384 + gh * 64 + c4;
                const int iv4 = bc * 32768 + gh * 64 + c4;
                st4(xout, j4, xp);
                st4(xtout, j4, xtp[k]);
                st4(uout, iv4, uu0);
                st4(uout, iv4 + 16384, uu1);
            } else {
                xreg[k] = xp;
                if (rr >= 1) ((float4*)(sxt + rr * 256))[c4] = xtp[k];
                if (trow == 0 && k == 0) st4_coh(xf + (Q * NBLK + blk) * 256 + c4 * 4, xp);
            }
        }
        if (s == KSTEPS) break;

        // ---- redundant halo row r0+8 (wave 0, tile<31; always interior in h) ----
        if (trow == 0 && tile < 31) {
            float4 h0, h1;
            h0.x = v0h.x*s0; h0.y = v0h.y*s0; h0.z = v0h.z*s0; h0.w = v0h.w*s0;
            h1.x = v1h.x*s1; h1.y = v1h.y*s1; h1.z = v1h.z*s1; h1.w = v1h.w*s1;
            float4 vmh = ((float4*)(sv0 + 7 * 256))[c4];
            float nt0 = vmh.x*s0 - h0.x, nt1 = vmh.y*s0 - h0.y,
                  nt2 = vmh.z*s0 - h0.z, nt3 = vmh.w*s0 - h0.w;
            float hul = __shfl_up(h1.w, 1, 64);
            if (c4 > 0) nt0 += hul;
            nt1 += h1.x; nt2 += h1.y; nt3 += h1.z;
            nt0 -= h1.x; nt1 -= h1.y; nt2 -= h1.z;
            if (c4 < 63) nt3 -= h1.w;
            float4 xph, xth;
            xph.x = (xoh.x + tau * (yhalo.x - nt0)) * inv;
            xph.y = (xoh.y + tau * (yhalo.y - nt1)) * inv;
            xph.z = (xoh.z + tau * (yhalo.z - nt2)) * inv;
            xph.w = (xoh.w + tau * (yhalo.w - nt3)) * inv;
            xth.x = opc * xph.x - chi * xoh.x;
            xth.y = opc * xph.y - chi * xoh.y;
            xth.z = opc * xph.z - chi * xoh.z;
            xth.w = opc * xph.w - chi * xoh.w;
            ((float4*)(sxt + 8 * 256))[c4] = xth;
        }
        __syncthreads();

        // ---------------- phase A (step s) ----------------
        const float sigs = sigma / chi;
        float pa0 = 0.f, pa1 = 0.f;
        #pragma unroll
        for (int k = 0; k < 2; ++k) {
            const int rr = trow + 4 * k;
            const int gh = r0 + rr;
            float4 dh = mk4(0.f, 0.f, 0.f, 0.f);
            if (gh < Hh - 1) {
                float4 xn = ((const float4*)(sxt + (rr + 1) * 256))[c4];
                dh.x = xn.x - xtp[k].x; dh.y = xn.y - xtp[k].y;
                dh.z = xn.z - xtp[k].z; dh.w = xn.w - xtp[k].w;
            }
            float4 dw;
            dw.x = xtp[k].y - xtp[k].x; dw.y = xtp[k].z - xtp[k].y; dw.z = xtp[k].w - xtp[k].z;
            float xnx = __shfl_down(xtp[k].x, 1, 64);
            dw.w = (c4 < 63) ? (xnx - xtp[k].w) : 0.f;
            v0[k].x = fmaf(sigs, dh.x, u0[k].x); v0[k].y = fmaf(sigs, dh.y, u0[k].y);
            v0[k].z = fmaf(sigs, dh.z, u0[k].z); v0[k].w = fmaf(sigs, dh.w, u0[k].w);
            v1[k].x = fmaf(sigs, dw.x, u1[k].x); v1[k].y = fmaf(sigs, dw.y, u1[k].y);
            v1[k].z = fmaf(sigs, dw.z, u1[k].z); v1[k].w = fmaf(sigs, dw.w, u1[k].w);
            ((float4*)(sv0 + rr * 256))[c4] = v0[k];
            pa0 += v0[k].x*v0[k].x + v0[k].y*v0[k].y + v0[k].z*v0[k].z + v0[k].w*v0[k].w;
            pa1 += v1[k].x*v1[k].x + v1[k].y*v1[k].y + v1[k].z*v1[k].z + v1[k].w*v1[k].w;
            if (trow == 0 && k == 0) {
                st4_coh(v0f + (Q * NBLK + blk) * 256 + c4 * 4, v0[0]);
                st4_coh(v1f + (Q * NBLK + blk) * 256 + c4 * 4, v1[0]);
            }
            if (trow == 3 && k == 1) st4_coh(v0l + (Q * NBLK + blk) * 256 + c4 * 4, v0[1]);
        }
        #pragma unroll
        for (int m = 1; m < 64; m <<= 1) {
            pa0 += __shfl_xor(pa0, m, 64);
            pa1 += __shfl_xor(pa1, m, 64);
        }
        if (c4 == 0) pw[trow] = make_float2(pa0, pa1);
        __syncthreads();
        if (tid == 0) {
            float q0 = pw[0].x + pw[1].x + pw[2].x + pw[3].x;
            float q1 = pw[0].y + pw[1].y + pw[2].y + pw[3].y;
            st4_coh(parts + (Q * NBLK + blk) * 4, b ? mk4(0.f, 0.f, q0, q1) : mk4(q0, q1, 0.f, 0.f));
        }
        asm volatile("s_waitcnt vmcnt(0)" ::: "memory");
        __syncthreads();
        if (tid == 0) __hip_atomic_fetch_add(cnt, 1u, __ATOMIC_RELAXED, __HIP_MEMORY_SCOPE_AGENT);

        tau *= chi;
        sigma = sigs;
    }
}

extern "C" void kernel_launch(void* const* d_in, const int* in_sizes, int n_in,
                              void* d_out, int out_size, void* d_ws, size_t ws_size,
                              hipStream_t stream) {
    (void)in_sizes; (void)n_in; (void)out_size; (void)ws_size;
    const float* y     = (const float*)d_in[0];
    const float* lambd = (const float*)d_in[1];
    float* xout  = (float*)d_out;       // [0, NX)
    float* xtout = xout + NX;           // [NX, 2NX)
    float* uout  = xout + 2 * NX;       // [2NX, 2NX+NU)

    float* v0f   = (float*)d_ws;                 // [2][NBLK][256]
    float* v1f   = v0f + 2 * NBLK * 256;
    float* v0l   = v1f + 2 * NBLK * 256;
    float* xf    = v0l + 2 * NBLK * 256;
    float* parts = xf  + 2 * NBLK * 256;         // [2][NBLK][4]
    unsigned* cnt = (unsigned*)(parts + 2 * NBLK * 4);

    zero_cnt<<<1, 1, 0, stream>>>(cnt);
    cp_persist<<<NBLK, 256, 0, stream>>>(y, lambd, xout, xtout, uout,
                                         v0f, v1f, v0l, xf, parts, cnt);
}

// Round 7
// 270.903 us; speedup vs baseline: 1.5066x; 1.2757x over previous
//
#include <hip/hip_runtime.h>
#include <math.h>

constexpr int Cc = 3, Hh = 256;
constexpr int NX = 393216;   // 2*3*256*256
constexpr int R = 8;         // rows per block
constexpr int NBLK = 192;    // 6 images * 32 tiles  (<= 256 CUs: 1 block/CU)
constexpr int KSTEPS = 50;

using u64 = unsigned long long;
constexpr u64 SENT = 0x8000000080000000ull;  // (-0.0f,-0.0f): unreachable for sums of squares

__device__ __forceinline__ float4 ld4(const float* p, int i) { return ((const float4*)p)[i]; }
__device__ __forceinline__ void st4(float* p, int i, float4 v) { ((float4*)p)[i] = v; }
__device__ __forceinline__ float4 mk4(float a, float b, float c, float d) { return make_float4(a, b, c, d); }

// Coherent (cross-XCD) access via relaxed agent-scope atomics (sc1, bypass L2).
__device__ __forceinline__ float4 ld4_coh(const float* p) {
    union { float4 f; u64 q[2]; } r;
    const u64* q = (const u64*)p;
    r.q[0] = __hip_atomic_load(q + 0, __ATOMIC_RELAXED, __HIP_MEMORY_SCOPE_AGENT);
    r.q[1] = __hip_atomic_load(q + 1, __ATOMIC_RELAXED, __HIP_MEMORY_SCOPE_AGENT);
    return r.f;
}
__device__ __forceinline__ void st4_coh(float* p, float4 v) {
    union { float4 f; u64 q[2]; } r; r.f = v;
    u64* q = (u64*)p;
    __hip_atomic_store(q + 0, r.q[0], __ATOMIC_RELAXED, __HIP_MEMORY_SCOPE_AGENT);
    __hip_atomic_store(q + 1, r.q[1], __ATOMIC_RELAXED, __HIP_MEMORY_SCOPE_AGENT);
}

__global__ void init_parts(u64* parts) {
    int i = blockIdx.x * 256 + threadIdx.x;
    if (i < KSTEPS * NBLK) parts[i] = SENT;
}

__global__ void __launch_bounds__(256) cp_persist(
    const float* __restrict__ y, const float* __restrict__ lambd,
    float* __restrict__ xout, float* __restrict__ xtout, float* __restrict__ uout,
    float* __restrict__ v0f, float* __restrict__ v1f, float* __restrict__ v0l,
    float* __restrict__ xf, u64* __restrict__ parts)
{
    __shared__ float sxt[9 * 256];
    __shared__ float sv0[8 * 256];
    __shared__ float2 pw[4];
    const int tid = threadIdx.x;
    const int blk = blockIdx.x;
    const int bc = blk >> 5;           // image index [0,6)
    const int tile = blk & 31;         // [0,32)
    const int r0 = tile * R;
    const int c4 = tid & 63;
    const int trow = tid >> 6;         // [0,4)
    const int b = (bc >= Cc) ? 1 : 0;

    const float lamb = expf(lambd[0]);

    float4 yv[2], xreg[2], v0[2], v1[2], u0[2], u1[2], xtp[2];
    float4 yhalo = mk4(0.f, 0.f, 0.f, 0.f);
    if (trow == 0 && tile < 31) yhalo = ld4(y, bc * 16384 + (r0 + 8) * 64 + c4);

    // ---------------- init: x=y, v = nabla(y) (xt_0 = 0 so v_0 = u_0) ----------------
    {
        float pa0 = 0.f, pa1 = 0.f;
        #pragma unroll
        for (int k = 0; k < 2; ++k) {
            const int rr = trow + 4 * k;
            const int gh = r0 + rr;
            const int j4 = bc * 16384 + gh * 64 + c4;
            yv[k] = ld4(y, j4);
            xreg[k] = yv[k];
            float4 dh = mk4(0.f, 0.f, 0.f, 0.f);
            if (gh < Hh - 1) {
                float4 yn = ld4(y, j4 + 64);
                dh.x = yn.x - yv[k].x; dh.y = yn.y - yv[k].y;
                dh.z = yn.z - yv[k].z; dh.w = yn.w - yv[k].w;
            }
            float4 dw;
            dw.x = yv[k].y - yv[k].x; dw.y = yv[k].z - yv[k].y; dw.z = yv[k].w - yv[k].z;
            float ynx = __shfl_down(yv[k].x, 1, 64);
            dw.w = (c4 < 63) ? (ynx - yv[k].w) : 0.f;
            v0[k] = dh; v1[k] = dw;
            ((float4*)(sv0 + rr * 256))[c4] = dh;
            pa0 += dh.x*dh.x + dh.y*dh.y + dh.z*dh.z + dh.w*dh.w;
            pa1 += dw.x*dw.x + dw.y*dw.y + dw.z*dw.z + dw.w*dw.w;
        }
        if (trow == 0) {
            st4_coh(v0f + blk * 256 + c4 * 4, v0[0]);
            st4_coh(v1f + blk * 256 + c4 * 4, v1[0]);
            st4_coh(xf  + blk * 256 + c4 * 4, xreg[0]);
        }
        if (trow == 3) st4_coh(v0l + blk * 256 + c4 * 4, v0[1]);   // row 7
        #pragma unroll
        for (int m = 1; m < 64; m <<= 1) {
            pa0 += __shfl_xor(pa0, m, 64);
            pa1 += __shfl_xor(pa1, m, 64);
        }
        if (c4 == 0) pw[trow] = make_float2(pa0, pa1);
        asm volatile("s_waitcnt vmcnt(0)" ::: "memory");   // drain halo stores (per wave)
        __syncthreads();                                    // all waves drained + pw visible
        if (tid == 0) {
            union { float f[2]; u64 q; } pk;
            pk.f[0] = pw[0].x + pw[1].x + pw[2].x + pw[3].x;
            pk.f[1] = pw[0].y + pw[1].y + pw[2].y + pw[3].y;
            __hip_atomic_store(parts + blk, pk.q, __ATOMIC_RELAXED, __HIP_MEMORY_SCOPE_AGENT);
        }
    }

    float sigma = 0.20412414523193150818f;   // 0.5/sqrt(6)
    float tau   = sigma;

    for (int s = 1; s <= KSTEPS; ++s) {
        // ---------- data-as-barrier: poll step-(s-1) partials until all published ----------
        const u64* pbase = parts + (size_t)(s - 1) * NBLK;
        u64 w0, w1, w2;
        for (;;) {
            w0 = __hip_atomic_load(pbase + c4,       __ATOMIC_RELAXED, __HIP_MEMORY_SCOPE_AGENT);
            w1 = __hip_atomic_load(pbase + c4 + 64,  __ATOMIC_RELAXED, __HIP_MEMORY_SCOPE_AGENT);
            w2 = __hip_atomic_load(pbase + c4 + 128, __ATOMIC_RELAXED, __HIP_MEMORY_SCOPE_AGENT);
            bool ok = (w0 != SENT) && (w1 != SENT) && (w2 != SENT);
            if (__all(ok)) break;
            __builtin_amdgcn_s_sleep(1);
        }
        const int P = (s - 1) & 1, Q = s & 1;

        // early coherent neighbor loads (parts-visible => halos-visible; overlap with scales)
        float4 vmtop = mk4(0.f, 0.f, 0.f, 0.f);
        float4 v0h = vmtop, v1h = vmtop, xoh = vmtop;
        if (trow == 0) {
            if (tile > 0) vmtop = ld4_coh(v0l + (P * NBLK + blk - 1) * 256 + c4 * 4);
            if (tile < 31) {
                v0h = ld4_coh(v0f + (P * NBLK + blk + 1) * 256 + c4 * 4);
                v1h = ld4_coh(v1f + (P * NBLK + blk + 1) * 256 + c4 * 4);
                xoh = ld4_coh(xf  + (P * NBLK + blk + 1) * 256 + c4 * 4);
            }
        }

        // scales: group-sum the polled payloads (fixed order + butterfly; bit-identical
        // across lanes/waves/blocks). lane's blocks: c4 (b=0), c4+64 (b = c4>=32), c4+128 (b=1)
        float g0 = 0.f, g1 = 0.f, g2 = 0.f, g3 = 0.f;
        {
            union { u64 q; float f[2]; } a0, a1, a2;
            a0.q = w0; a1.q = w1; a2.q = w2;
            g0 += a0.f[0]; g1 += a0.f[1];
            if (c4 < 32) { g0 += a1.f[0]; g1 += a1.f[1]; }
            else         { g2 += a1.f[0]; g3 += a1.f[1]; }
            g2 += a2.f[0]; g3 += a2.f[1];
            #pragma unroll
            for (int m = 1; m < 64; m <<= 1) {
                g0 += __shfl_xor(g0, m, 64);
                g1 += __shfl_xor(g1, m, 64);
                g2 += __shfl_xor(g2, m, 64);
                g3 += __shfl_xor(g3, m, 64);
            }
        }
        const float s0 = lamb / fmaxf(sqrtf(b ? g2 : g0), lamb);
        const float s1 = lamb / fmaxf(sqrtf(b ? g3 : g1), lamb);
        const float chi = 1.0f / sqrtf(1.0f + tau);
        const float inv = 1.0f / (1.0f + tau);
        const float opc = 1.0f + chi;

        // ---------------- phase B (step s-1) ----------------
        #pragma unroll
        for (int k = 0; k < 2; ++k) {
            const int rr = trow + 4 * k;
            const int gh = r0 + rr;
            float4 uu0, uu1;
            uu0.x = v0[k].x*s0; uu0.y = v0[k].y*s0; uu0.z = v0[k].z*s0; uu0.w = v0[k].w*s0;
            uu1.x = v1[k].x*s1; uu1.y = v1[k].y*s1; uu1.z = v1[k].z*s1; uu1.w = v1[k].w*s1;
            float4 vm = (k == 0) ? ((trow > 0) ? ((float4*)(sv0 + (trow - 1) * 256))[c4] : vmtop)
                                 : ((float4*)(sv0 + (trow + 3) * 256))[c4];
            float nt0 = 0.f, nt1 = 0.f, nt2 = 0.f, nt3 = 0.f;
            if (gh > 0) { nt0 += vm.x*s0; nt1 += vm.y*s0; nt2 += vm.z*s0; nt3 += vm.w*s0; }
            if (gh < Hh - 1) { nt0 -= uu0.x; nt1 -= uu0.y; nt2 -= uu0.z; nt3 -= uu0.w; }
            float ul = __shfl_up(uu1.w, 1, 64);
            if (c4 > 0) nt0 += ul;
            nt1 += uu1.x; nt2 += uu1.y; nt3 += uu1.z;
            nt0 -= uu1.x; nt1 -= uu1.y; nt2 -= uu1.z;
            if (c4 < 63) nt3 -= uu1.w;
            float4 xp;
            xp.x = (xreg[k].x + tau * (yv[k].x - nt0)) * inv;
            xp.y = (xreg[k].y + tau * (yv[k].y - nt1)) * inv;
            xp.z = (xreg[k].z + tau * (yv[k].z - nt2)) * inv;
            xp.w = (xreg[k].w + tau * (yv[k].w - nt3)) * inv;
            xtp[k].x = opc * xp.x - chi * xreg[k].x;
            xtp[k].y = opc * xp.y - chi * xreg[k].y;
            xtp[k].z = opc * xp.z - chi * xreg[k].z;
            xtp[k].w = opc * xp.w - chi * xreg[k].w;
            u0[k] = uu0; u1[k] = uu1;
            if (s == KSTEPS) {
                const int j4 = bc * 16384 + gh * 64 + c4;
                const int iv4 = bc * 32768 + gh * 64 + c4;
                st4(xout, j4, xp);
                st4(xtout, j4, xtp[k]);
                st4(uout, iv4, uu0);
                st4(uout, iv4 + 16384, uu1);
            } else {
                xreg[k] = xp;
                if (rr >= 1) ((float4*)(sxt + rr * 256))[c4] = xtp[k];
                if (trow == 0 && k == 0) st4_coh(xf + (Q * NBLK + blk) * 256 + c4 * 4, xp);
            }
        }
        if (s == KSTEPS) break;

        // ---- redundant halo row r0+8 (wave 0, tile<31; always interior in h) ----
        if (trow == 0 && tile < 31) {
            float4 h0, h1;
            h0.x = v0h.x*s0; h0.y = v0h.y*s0; h0.z = v0h.z*s0; h0.w = v0h.w*s0;
            h1.x = v1h.x*s1; h1.y = v1h.y*s1; h1.z = v1h.z*s1; h1.w = v1h.w*s1;
            float4 vmh = ((float4*)(sv0 + 7 * 256))[c4];
            float nt0 = vmh.x*s0 - h0.x, nt1 = vmh.y*s0 - h0.y,
                  nt2 = vmh.z*s0 - h0.z, nt3 = vmh.w*s0 - h0.w;
            float hul = __shfl_up(h1.w, 1, 64);
            if (c4 > 0) nt0 += hul;
            nt1 += h1.x; nt2 += h1.y; nt3 += h1.z;
            nt0 -= h1.x; nt1 -= h1.y; nt2 -= h1.z;
            if (c4 < 63) nt3 -= h1.w;
            float4 xph, xth;
            xph.x = (xoh.x + tau * (yhalo.x - nt0)) * inv;
            xph.y = (xoh.y + tau * (yhalo.y - nt1)) * inv;
            xph.z = (xoh.z + tau * (yhalo.z - nt2)) * inv;
            xph.w = (xoh.w + tau * (yhalo.w - nt3)) * inv;
            xth.x = opc * xph.x - chi * xoh.x;
            xth.y = opc * xph.y - chi * xoh.y;
            xth.z = opc * xph.z - chi * xoh.z;
            xth.w = opc * xph.w - chi * xoh.w;
            ((float4*)(sxt + 8 * 256))[c4] = xth;
        }
        __syncthreads();

        // ---------------- phase A (step s) ----------------
        const float sigs = sigma / chi;
        float pa0 = 0.f, pa1 = 0.f;
        #pragma unroll
        for (int k = 0; k < 2; ++k) {
            const int rr = trow + 4 * k;
            const int gh = r0 + rr;
            float4 dh = mk4(0.f, 0.f, 0.f, 0.f);
            if (gh < Hh - 1) {
                float4 xn = ((const float4*)(sxt + (rr + 1) * 256))[c4];
                dh.x = xn.x - xtp[k].x; dh.y = xn.y - xtp[k].y;
                dh.z = xn.z - xtp[k].z; dh.w = xn.w - xtp[k].w;
            }
            float4 dw;
            dw.x = xtp[k].y - xtp[k].x; dw.y = xtp[k].z - xtp[k].y; dw.z = xtp[k].w - xtp[k].z;
            float xnx = __shfl_down(xtp[k].x, 1, 64);
            dw.w = (c4 < 63) ? (xnx - xtp[k].w) : 0.f;
            v0[k].x = fmaf(sigs, dh.x, u0[k].x); v0[k].y = fmaf(sigs, dh.y, u0[k].y);
            v0[k].z = fmaf(sigs, dh.z, u0[k].z); v0[k].w = fmaf(sigs, dh.w, u0[k].w);
            v1[k].x = fmaf(sigs, dw.x, u1[k].x); v1[k].y = fmaf(sigs, dw.y, u1[k].y);
            v1[k].z = fmaf(sigs, dw.z, u1[k].z); v1[k].w = fmaf(sigs, dw.w, u1[k].w);
            ((float4*)(sv0 + rr * 256))[c4] = v0[k];
            pa0 += v0[k].x*v0[k].x + v0[k].y*v0[k].y + v0[k].z*v0[k].z + v0[k].w*v0[k].w;
            pa1 += v1[k].x*v1[k].x + v1[k].y*v1[k].y + v1[k].z*v1[k].z + v1[k].w*v1[k].w;
            if (trow == 0 && k == 0) {
                st4_coh(v0f + (Q * NBLK + blk) * 256 + c4 * 4, v0[0]);
                st4_coh(v1f + (Q * NBLK + blk) * 256 + c4 * 4, v1[0]);
            }
            if (trow == 3 && k == 1) st4_coh(v0l + (Q * NBLK + blk) * 256 + c4 * 4, v0[1]);
        }
        #pragma unroll
        for (int m = 1; m < 64; m <<= 1) {
            pa0 += __shfl_xor(pa0, m, 64);
            pa1 += __shfl_xor(pa1, m, 64);
        }
        if (c4 == 0) pw[trow] = make_float2(pa0, pa1);
        asm volatile("s_waitcnt vmcnt(0)" ::: "memory");   // drain this wave's halo stores
        __syncthreads();                                    // all waves drained + pw visible
        if (tid == 0) {
            union { float f[2]; u64 q; } pk;
            pk.f[0] = pw[0].x + pw[1].x + pw[2].x + pw[3].x;
            pk.f[1] = pw[0].y + pw[1].y + pw[2].y + pw[3].y;
            __hip_atomic_store(parts + (size_t)s * NBLK + blk, pk.q,
                               __ATOMIC_RELAXED, __HIP_MEMORY_SCOPE_AGENT);
        }

        tau *= chi;
        sigma = sigs;
    }
}

extern "C" void kernel_launch(void* const* d_in, const int* in_sizes, int n_in,
                              void* d_out, int out_size, void* d_ws, size_t ws_size,
                              hipStream_t stream) {
    (void)in_sizes; (void)n_in; (void)out_size; (void)ws_size;
    const float* y     = (const float*)d_in[0];
    const float* lambd = (const float*)d_in[1];
    float* xout  = (float*)d_out;       // [0, NX)
    float* xtout = xout + NX;           // [NX, 2NX)
    float* uout  = xout + 2 * NX;       // [2NX, 2NX+NU)

    float* v0f = (float*)d_ws;                    // [2][NBLK][256]
    float* v1f = v0f + 2 * NBLK * 256;
    float* v0l = v1f + 2 * NBLK * 256;
    float* xf  = v0l + 2 * NBLK * 256;
    u64* parts = (u64*)(xf + 2 * NBLK * 256);     // [KSTEPS][NBLK]

    init_parts<<<(KSTEPS * NBLK + 255) / 256, 256, 0, stream>>>(parts);
    cp_persist<<<NBLK, 256, 0, stream>>>(y, lambd, xout, xtout, uout,
                                         v0f, v1f, v0l, xf, parts);
}